// Round 4
// baseline (216.235 us; speedup 1.0000x reference)
//
#include <hip/hip_runtime.h>
#include <math.h>

// Problem constants
#define M_TOKENS 16384               // B*S = 4*4096
#define E_EXPERTS 64
#define K_DIM 2048
#define KSPLIT 4
#define KCHUNK (K_DIM / KSPLIT)      // 512
#define PSTRIDE (KSPLIT * E_EXPERTS) // 256 floats per token in partials
#define TPW 16                       // tokens per wave
#define WPB 8                        // waves per block (512 threads)
#define TPB2 (TPW * WPB)             // 128 tokens per block
#define SK 128                       // k-depth per LDS stage (32KB)
#define NS (KCHUNK / SK)             // 4 stages

// ---------------------------------------------------------------------------
// Gates kernel, lane=expert dataflow.
//  - W chunk staged in LDS [k][64] (linear copy, no transpose). Read back
//    ds_read_b32, 64 consecutive lanes -> 2-way bank alias = free.
//  - x read as wave-uniform broadcast dwordx4 -> 1 cacheline per instruction
//    (fixes round-3's 64-lines-per-instr TA oversubscription).
//  - Each wave: 16 tokens x 512 k -> 8192 FMA instrs; per kb4 iter:
//    4 ds_read + 16 x-loads + 64 FMAs.
//  - LDS double buffer, ONE barrier per stage: next-stage global->reg loads
//    issued before the barrier, LDS write after compute; buffer being
//    written was last read before the PREVIOUS barrier -> race-free.
//  - FMA order per (token, expert, kc): k ascending (s, kb, kk) -> partials
//    bit-identical to rounds 1-3.
// ---------------------------------------------------------------------------
__global__ __launch_bounds__(512, 4) void gates_kernel(
    const float* __restrict__ x, const float* __restrict__ W,
    float* __restrict__ part) {
  __shared__ float wlds[2][SK * E_EXPERTS];  // 2 x 32KB

  const int tid = threadIdx.x;
  const int lane = tid & 63;
  const int w = __builtin_amdgcn_readfirstlane(tid >> 6);
  const int tg = blockIdx.x >> 2;
  const int kc = blockIdx.x & 3;
  const int kbase = kc * KCHUNK;
  const int tok0 = tg * TPB2 + w * TPW;

  const float* xw = x + (size_t)tok0 * K_DIM + kbase;
  const float* wsrc = W + (size_t)kbase * E_EXPERTS;

  float acc[TPW];
#pragma unroll
  for (int t = 0; t < TPW; ++t) acc[t] = 0.0f;

  float4 stg[4];

  // stage tile = SK*64 floats = 8192; thread covers 4 float4 at
  // float offset (tid + 512*j)*4 — linear, fully coalesced, no transpose.
#define LOADS(s)                                                              \
  do {                                                                        \
    const float* src = wsrc + (size_t)(s) * SK * E_EXPERTS;                   \
    _Pragma("unroll") for (int j = 0; j < 4; ++j)                             \
        stg[j] = *reinterpret_cast<const float4*>(src + (tid + 512 * j) * 4); \
  } while (0)

#define WRITES(s)                                                             \
  do {                                                                        \
    float* dst = wlds[(s) & 1];                                               \
    _Pragma("unroll") for (int j = 0; j < 4; ++j)                             \
        *reinterpret_cast<float4*>(dst + (tid + 512 * j) * 4) = stg[j];       \
  } while (0)

  LOADS(0);
  WRITES(0);

  for (int s = 0; s < NS; ++s) {
    if (s + 1 < NS) LOADS(s + 1);   // global->reg, overlaps barrier+compute
    __syncthreads();                // stage s LDS writes visible everywhere

    const float* wb = wlds[s & 1];
    const float* xs = xw + s * SK;

    for (int kb = 0; kb < SK; kb += 4) {
      float wv[4];
#pragma unroll
      for (int kk = 0; kk < 4; ++kk)
        wv[kk] = wb[(kb + kk) * E_EXPERTS + lane];
      // two token-groups of 8 to cap register liveness (~32 VGPR for xv)
#pragma unroll
      for (int g = 0; g < 2; ++g) {
        float4 xv[8];
#pragma unroll
        for (int t8 = 0; t8 < 8; ++t8)
          xv[t8] = *reinterpret_cast<const float4*>(
              xs + (size_t)(g * 8 + t8) * K_DIM + kb);
#pragma unroll
        for (int kk = 0; kk < 4; ++kk) {
#pragma unroll
          for (int t8 = 0; t8 < 8; ++t8)
            acc[g * 8 + t8] = fmaf(((const float*)&xv[t8])[kk], wv[kk],
                                   acc[g * 8 + t8]);
        }
      }
    }

    if (s + 1 < NS) WRITES(s + 1);  // other buffer; safe (see header comment)
  }
#undef LOADS
#undef WRITES

  // store: 64 lanes write 256B consecutive per token -> coalesced
  float* p = part + (size_t)tok0 * PSTRIDE + kc * E_EXPERTS + lane;
#pragma unroll
  for (int t = 0; t < TPW; ++t) p[(size_t)t * PSTRIDE] = acc[t];
}

// ---------------------------------------------------------------------------
// Reduce + bias + top-2 + softmax (unchanged from round 3 — passed exact).
// ---------------------------------------------------------------------------
__global__ __launch_bounds__(64) void reduce_topk_kernel(
    const float* __restrict__ part, const float* __restrict__ bias,
    float* __restrict__ out) {
  const int t = blockIdx.x * 64 + threadIdx.x;
  const float4* p = reinterpret_cast<const float4*>(part + (size_t)t * PSTRIDE);
  const float4* b4 = reinterpret_cast<const float4*>(bias);

  float m1 = -INFINITY, m2 = -INFINITY;
  int i1 = 0, i2 = 0;

#pragma unroll 4
  for (int e4 = 0; e4 < 16; ++e4) {
    float4 a = p[e4];        // kc = 0
    float4 b = p[16 + e4];   // kc = 1
    float4 c = p[32 + e4];   // kc = 2
    float4 d = p[48 + e4];   // kc = 3
    float4 bb = b4[e4];
    float g[4];
    g[0] = bb.x + a.x; g[0] += b.x; g[0] += c.x; g[0] += d.x;
    g[1] = bb.y + a.y; g[1] += b.y; g[1] += c.y; g[1] += d.y;
    g[2] = bb.z + a.z; g[2] += b.z; g[2] += c.z; g[2] += d.z;
    g[3] = bb.w + a.w; g[3] += b.w; g[3] += c.w; g[3] += d.w;
#pragma unroll
    for (int j = 0; j < 4; ++j) {
      int e = e4 * 4 + j;
      if (g[j] > m1) {
        m2 = m1; i2 = i1;
        m1 = g[j]; i1 = e;
      } else if (g[j] > m2) {
        m2 = g[j]; i2 = e;
      }
    }
  }

  float w0 = 1.0f / (1.0f + expf(m2 - m1));
  out[2 * t + 0] = w0;
  out[2 * t + 1] = 1.0f - w0;
  float* oidx = out + 2 * (size_t)M_TOKENS;
  oidx[2 * t + 0] = (float)i1;
  oidx[2 * t + 1] = (float)i2;
}

// ---------------------------------------------------------------------------
// Fallback (proven correct in round 1): fully fused, no workspace.
// ---------------------------------------------------------------------------
__global__ __launch_bounds__(64) void router_fused_kernel(
    const float* __restrict__ x, const float* __restrict__ W,
    const float* __restrict__ bias, float* __restrict__ out) {
  const int t = blockIdx.x * 64 + threadIdx.x;
  const float* xrow = x + (size_t)t * K_DIM;

  float acc[E_EXPERTS];
#pragma unroll
  for (int e = 0; e < E_EXPERTS; ++e) acc[e] = 0.0f;

  for (int k4 = 0; k4 < K_DIM; k4 += 4) {
    float4 xv = *reinterpret_cast<const float4*>(xrow + k4);
    float xs[4] = {xv.x, xv.y, xv.z, xv.w};
#pragma unroll
    for (int kk = 0; kk < 4; ++kk) {
      const float* wrow = W + (size_t)(k4 + kk) * E_EXPERTS;
#pragma unroll
      for (int e = 0; e < E_EXPERTS; ++e) acc[e] = fmaf(xs[kk], wrow[e], acc[e]);
    }
  }

  float m1 = -INFINITY, m2 = -INFINITY;
  int i1 = 0, i2 = 0;
#pragma unroll
  for (int e = 0; e < E_EXPERTS; ++e) {
    float g = acc[e] + bias[e];
    if (g > m1) {
      m2 = m1; i2 = i1;
      m1 = g; i1 = e;
    } else if (g > m2) {
      m2 = g; i2 = e;
    }
  }

  float w0 = 1.0f / (1.0f + expf(m2 - m1));
  out[2 * t + 0] = w0;
  out[2 * t + 1] = 1.0f - w0;
  float* oidx = out + 2 * (size_t)M_TOKENS;
  oidx[2 * t + 0] = (float)i1;
  oidx[2 * t + 1] = (float)i2;
}

extern "C" void kernel_launch(void* const* d_in, const int* in_sizes, int n_in,
                              void* d_out, int out_size, void* d_ws, size_t ws_size,
                              hipStream_t stream) {
  const float* x = (const float*)d_in[0];
  const float* W = (const float*)d_in[1];
  const float* b = (const float*)d_in[2];
  float* out = (float*)d_out;

  const size_t need = (size_t)M_TOKENS * PSTRIDE * sizeof(float);
  if (ws_size >= need) {
    float* part = (float*)d_ws;
    gates_kernel<<<(M_TOKENS / TPB2) * KSPLIT, 512, 0, stream>>>(x, W, part);
    reduce_topk_kernel<<<M_TOKENS / 64, 64, 0, stream>>>(part, b, out);
  } else {
    router_fused_kernel<<<M_TOKENS / 64, 64, 0, stream>>>(x, W, b, out);
  }
}